// Round 4
// baseline (618.843 us; speedup 1.0000x reference)
//
#include <hip/hip_runtime.h>
#include <hip/hip_bf16.h>

typedef __attribute__((ext_vector_type(8))) short short8;
typedef __attribute__((ext_vector_type(4))) float f32x4;

// pack 8 fp32 -> 8 bf16 (RNE) as one short8 (4 VGPRs)
__device__ __forceinline__ short8 pack8(const f32x4& a, const f32x4& b) {
    union { __hip_bfloat162 h[4]; short8 s; } u;
    u.h[0] = __float22bfloat162_rn(make_float2(a[0], a[1]));
    u.h[1] = __float22bfloat162_rn(make_float2(a[2], a[3]));
    u.h[2] = __float22bfloat162_rn(make_float2(b[0], b[1]));
    u.h[3] = __float22bfloat162_rn(make_float2(b[2], b[3]));
    return u.s;
}

// Grid: 4096 blocks = 512 MLPs x 8 m-tiles. Block: 512 threads = 8 waves, 1M x 8N:
// each wave owns a 64-col stripe of n, reads its W1 slice global->reg directly
// (exactly once -> no LDS staging, NO BARRIERS in the K-loop). X[128][512] is
// staged once to LDS in bf16 fragment order (128KB) and is read-only afterwards.
__global__ __launch_bounds__(512, 2)
void ens_mlp_kernel(const float* __restrict__ X,
                    const float* __restrict__ W1,
                    const float* __restrict__ B1,
                    const float* __restrict__ W2,
                    const float* __restrict__ B2,
                    float* __restrict__ out)
{
    extern __shared__ char smem[];   // 128KB: A frags [8 m-frag][16 ks][64 granule][16B]
    const int t    = threadIdx.x;
    const int lane = t & 63;
    const int wv   = t >> 6;        // 0..7 (N-stripe wave index)
    const int nc   = lane & 15;     // col within 16x16 frag
    const int kq   = lane >> 4;     // k-chunk 0..3 within K=32

    // XCD-aware decode: 8 m-blocks of the same km land adjacent on one XCD.
    const int bb  = blockIdx.x;
    const int xcd = bb & 7;
    const int j   = bb >> 3;
    const int km  = xcd * 64 + (j >> 3);  // MLP index 0..511
    const int mt  = j & 7;                // m-tile 0..7

    const float* __restrict__ W1k = W1 + (size_t)km * (512 * 512);
    const float* __restrict__ Xm  = X + (size_t)mt * 128 * 512;

    // ---- prologue: stage X[128][512] -> LDS bf16, MFMA-fragment order ----
    // thread t: row r = t>>2, k-chunk cc = t&3 (+4q); granule lane-pos
    // l = (r&15) | (cc<<4) inside slot (m-frag = r>>4, ks = q).
    {
        const int r  = t >> 2, cc = t & 3;
        const float* srow = Xm + r * 512 + cc * 8;
        char* dbase = smem + ((r >> 4) * 16) * 1024 + (((cc << 4) | (r & 15)) * 16);
#pragma unroll
        for (int q = 0; q < 16; ++q) {
            f32x4 a = *(const f32x4*)(srow + q * 32);
            f32x4 b = *(const f32x4*)(srow + q * 32 + 4);
            *(short8*)(dbase + q * 1024) = pack8(a, b);
        }
    }

    f32x4 acc[8][4];
#pragma unroll
    for (int i = 0; i < 8; ++i)
#pragma unroll
        for (int p = 0; p < 4; ++p)
            acc[i][p] = (f32x4)0.0f;

    // per-thread W1 fragment sources: lane holds W1k[n][k0..k0+7],
    // n = (wv*4+p)*16 + nc, k0 = ks*32 + kq*8
    const float* bsrc0 = W1k + (size_t)((wv * 4 + 0) * 16 + nc) * 512 + kq * 8;
    const float* bsrc1 = W1k + (size_t)((wv * 4 + 1) * 16 + nc) * 512 + kq * 8;
    const float* bsrc2 = W1k + (size_t)((wv * 4 + 2) * 16 + nc) * 512 + kq * 8;
    const float* bsrc3 = W1k + (size_t)((wv * 4 + 3) * 16 + nc) * 512 + kq * 8;

    f32x4 cA[4][2], cB[4][2];   // two named fp32 staging sets (1-deep pipeline)

    auto loadB = [&](f32x4 (&c)[4][2], int ks) {
        const int o = ks * 32;
        c[0][0] = *(const f32x4*)(bsrc0 + o); c[0][1] = *(const f32x4*)(bsrc0 + o + 4);
        c[1][0] = *(const f32x4*)(bsrc1 + o); c[1][1] = *(const f32x4*)(bsrc1 + o + 4);
        c[2][0] = *(const f32x4*)(bsrc2 + o); c[2][1] = *(const f32x4*)(bsrc2 + o + 4);
        c[3][0] = *(const f32x4*)(bsrc3 + o); c[3][1] = *(const f32x4*)(bsrc3 + o + 4);
    };

    auto compute = [&](f32x4 (&c)[4][2], int ks) {
        const char* abase = smem + ks * 1024 + (lane << 4);
        short8 bv[4];
#pragma unroll
        for (int p = 0; p < 4; ++p)
            bv[p] = pack8(c[p][0], c[p][1]);
        short8 av[4];
#pragma unroll
        for (int i = 0; i < 4; ++i)
            av[i] = *(const short8*)(abase + i * 16384);
#pragma unroll
        for (int i = 0; i < 4; ++i)
#pragma unroll
            for (int p = 0; p < 4; ++p)
                acc[i][p] = __builtin_amdgcn_mfma_f32_16x16x32_bf16(av[i], bv[p], acc[i][p], 0, 0, 0);
#pragma unroll
        for (int i = 0; i < 4; ++i)
            av[i] = *(const short8*)(abase + (i + 4) * 16384);
#pragma unroll
        for (int i = 0; i < 4; ++i)
#pragma unroll
            for (int p = 0; p < 4; ++p)
                acc[i + 4][p] = __builtin_amdgcn_mfma_f32_16x16x32_bf16(av[i], bv[p], acc[i + 4][p], 0, 0, 0);
    };

    loadB(cA, 0);            // overlap with barrier
    __syncthreads();         // X staged; LDS read-only from here -> no more barriers

#pragma unroll 1
    for (int ks = 0; ks < 16; ks += 2) {
        loadB(cB, ks + 1);             // issue next loads first (hide L2 latency)
        compute(cA, ks);
        if (ks + 2 < 16) loadB(cA, ks + 2);
        compute(cB, ks + 1);
    }

    // ---- fused epilogue: out[b,km] = sum_n relu(h + b1[n]) * w2[n] + b2 ----
    float b1v[4], w2v[4];
#pragma unroll
    for (int p = 0; p < 4; ++p) {
        int n = (wv * 4 + p) * 16 + nc;
        b1v[p] = B1[km * 512 + n];
        w2v[p] = W2[km * 512 + n];
    }

    __syncthreads();                 // all waves done reading X LDS
    float* lout = (float*)smem;      // reuse: [128 rows][stride 9] partials

#pragma unroll
    for (int i = 0; i < 8; ++i) {
#pragma unroll
        for (int r = 0; r < 4; ++r) {
            float s = 0.f;
#pragma unroll
            for (int p = 0; p < 4; ++p) {
                float h = acc[i][p][r] + b1v[p];
                h = h > 0.f ? h : 0.f;
                s += h * w2v[p];
            }
            // reduce over the 16 lanes holding different n columns
#pragma unroll
            for (int d = 1; d < 16; d <<= 1)
                s += __shfl_xor(s, d, 64);
            if (nc == 0) {
                int row = i * 16 + kq * 4 + r;   // C/D: row = (lane>>4)*4 + reg
                lout[row * 9 + wv] = s;
            }
        }
    }
    __syncthreads();
    if (t < 128) {
        float s = B2[km];
#pragma unroll
        for (int w = 0; w < 8; ++w)
            s += lout[t * 9 + w];
        int brow = mt * 128 + t;
        // out[b, e, o] with k = o*E + e  ->  flat b*512 + (k%8)*64 + (k/8)
        out[(size_t)brow * 512 + (km & 7) * 64 + (km >> 3)] = s;
    }
}

extern "C" void kernel_launch(void* const* d_in, const int* in_sizes, int n_in,
                              void* d_out, int out_size, void* d_ws, size_t ws_size,
                              hipStream_t stream) {
    const float* X  = (const float*)d_in[0];
    const float* W1 = (const float*)d_in[1];
    const float* B1 = (const float*)d_in[2];
    const float* W2 = (const float*)d_in[3];
    const float* B2 = (const float*)d_in[4];
    float* out = (float*)d_out;

    ens_mlp_kernel<<<dim3(4096), dim3(512), 131072, stream>>>(X, W1, B1, W2, B2, out);
}

// Round 5
// 420.709 us; speedup vs baseline: 1.4710x; 1.4710x over previous
//
#include <hip/hip_runtime.h>
#include <hip/hip_bf16.h>

typedef __attribute__((ext_vector_type(8))) short short8;
typedef __attribute__((ext_vector_type(4))) float f32x4;

// pack 8 fp32 -> 8 bf16 (RNE) as one short8 (4 VGPRs)
__device__ __forceinline__ short8 pack8(const f32x4& a, const f32x4& b) {
    union { __hip_bfloat162 h[4]; short8 s; } u;
    u.h[0] = __float22bfloat162_rn(make_float2(a[0], a[1]));
    u.h[1] = __float22bfloat162_rn(make_float2(a[2], a[3]));
    u.h[2] = __float22bfloat162_rn(make_float2(b[0], b[1]));
    u.h[3] = __float22bfloat162_rn(make_float2(b[2], b[3]));
    return u.s;
}

// Granule swizzle (involution, applied to store AND load): injects the k-oct
// bits (g>>4) into bank bits 1-2 so staging ds_write_b128 is 2-way (free).
__device__ __forceinline__ int swz(int g) { return g ^ (((g >> 4) & 3) << 1); }

// ---- m201-style 8-phase counted-vmcnt GEMM, reg-staged fp32->bf16 ----
// Grid: 4096 = 512 km x 4 mt x 2 nt. Block: 512 thr = 8 waves (2M x 4N).
// Tile: BM=256 x BN=256 x BK=64. LDS: 2 buf x (A 32KB | B 32KB) = 128KB.
// K-tiles kt=0..7, 4 phases each (global phase g=4kt+p):
//   phase p: ds_read quadrant (i-half=p&1, kk=p>>1) of tile kt [cur buf]
//            vmcnt(4) -> cvt+write quarter type p of tile kt+1 [other buf]
//            issue 4 loads of quarter type (p+2)&3 (tile kt+1 or kt+2)
//            lgkmcnt(0); sched_barrier; s_barrier; setprio(1) 16 MFMA setprio(0)
// Race audit: writes always target buf[(kt+1)&1] != read buf[kt&1]; a wave
// entering phase (kt+1,0) ds_reads only after ALL waves passed (kt,3)'s
// barrier, which follows their lgkmcnt(0)-drained writes of tile kt+1.
// vmcnt: each phase issues exactly 4 loads; quarter written at phase g was
// issued at g-2 with only g-1's 4 loads younger -> vmcnt(4) suffices
// (FIFO retire). Tail: (6,3) has no (6,2) issue -> vmcnt(0).
#define PHASE(P, KTV, SET, DOW, DOI, VM)                                          \
  do {                                                                            \
    const char* rb_ = smem + ((KTV) & 1) * 65536;                                 \
    _Pragma("unroll") for (int ii = 0; ii < 4; ++ii)                              \
        av[ii] = *(const short8*)(rb_ +                                           \
            (((wm * 8 + ((P) & 1) * 4 + ii) * 2 + ((P) >> 1)) << 10) + rdo);      \
    if (((P) & 1) == 0) {                                                         \
      _Pragma("unroll") for (int pp = 0; pp < 4; ++pp)                            \
          bv[pp] = *(const short8*)(rb_ + 32768 +                                 \
              (((wn * 4 + pp) * 2 + ((P) >> 1)) << 10) + rdo);                    \
    }                                                                             \
    if (DOW) {                                                                    \
      asm volatile("s_waitcnt vmcnt(" #VM ")" ::: "memory");                      \
      short8 w0_ = pack8(SET[0], SET[1]);                                         \
      short8 w1_ = pack8(SET[2], SET[3]);                                         \
      char* wdst_ = smem + (((KTV) + 1) & 1) * 65536 +                            \
                    (((P) >= 2) ? 32768 : 0) + (((P) & 1) * 16384) + wfrag;       \
      *(short8*)wdst_ = w0_;                                                      \
      *(short8*)(wdst_ + 1024) = w1_;                                             \
    }                                                                             \
    if (DOI) {                                                                    \
      const float* isrc_ = (((P) >= 2) ? (As + ((KTV) + 2) * 64)                  \
                                       : (Bs + ((KTV) + 1) * 64)) +               \
                           (((P) & 1) ? 65536 : 0);                               \
      SET[0] = *(const f32x4*)isrc_;                                              \
      SET[1] = *(const f32x4*)(isrc_ + 4);                                        \
      SET[2] = *(const f32x4*)(isrc_ + 32);                                       \
      SET[3] = *(const f32x4*)(isrc_ + 36);                                       \
    }                                                                             \
    asm volatile("s_waitcnt lgkmcnt(0)" ::: "memory");                            \
    __builtin_amdgcn_sched_barrier(0);                                            \
    __builtin_amdgcn_s_barrier();                                                 \
    __builtin_amdgcn_s_setprio(1);                                                \
    _Pragma("unroll") for (int ii = 0; ii < 4; ++ii)                              \
        _Pragma("unroll") for (int pp = 0; pp < 4; ++pp)                          \
            acc[((P) & 1) * 4 + ii][pp] = __builtin_amdgcn_mfma_f32_16x16x32_bf16(\
                av[ii], bv[pp], acc[((P) & 1) * 4 + ii][pp], 0, 0, 0);            \
    __builtin_amdgcn_s_setprio(0);                                                \
    __builtin_amdgcn_sched_barrier(0);                                            \
  } while (0)

__global__ __launch_bounds__(512, 2)
void ens_mlp_kernel(const float* __restrict__ X,
                    const float* __restrict__ W1,
                    const float* __restrict__ B1,
                    const float* __restrict__ W2,
                    const float* __restrict__ B2,
                    float* __restrict__ out)
{
    extern __shared__ char smem[];
    const int t    = threadIdx.x;
    const int lane = t & 63;
    const int wv   = t >> 6;
    const int wm   = wv >> 2;     // 0..1
    const int wn   = wv & 3;      // 0..3

    // XCD-aware decode: 8 blocks of the same km adjacent on one XCD.
    const int bb  = blockIdx.x;
    const int xcd = bb & 7;
    const int j   = bb >> 3;
    const int km  = xcd * 64 + (j >> 3);   // 0..511
    const int sub = j & 7;
    const int mt  = sub >> 1;              // 0..3 (256-row batch tile)
    const int nt  = sub & 1;               // 0..1 (256-col n half)

    const float* __restrict__ W1k = W1 + (size_t)km * (512 * 512);

    // staging identity: thread handles row lr, k-octs {c, c+4} of each quarter
    const int lr = t >> 2;                 // 0..127
    const int c  = t & 3;
    const float* As = X   + (size_t)(mt * 256 + lr) * 512 + c * 8;
    const float* Bs = W1k + (size_t)(nt * 256 + lr) * 512 + c * 8;
    const int wfrag = ((lr >> 4) << 11) + (swz((c << 4) | (lr & 15)) << 4);
    const int rdo   = swz(lane) << 4;      // fragment read offset (logical=lane)

    // ---- prologue: stage tile 0 (counted), prefetch q4,q5 of tile 1 ----
    f32x4 s0[4], s1[4];
    {
        f32x4 t0[4], t1[4], t2[4], t3[4];
        const float* q0 = As;              // A half0, tile0
        const float* q1 = As + 65536;      // A half1
        const float* q2 = Bs;              // B half0
        const float* q3 = Bs + 65536;      // B half1
        t0[0]=*(const f32x4*)q0; t0[1]=*(const f32x4*)(q0+4); t0[2]=*(const f32x4*)(q0+32); t0[3]=*(const f32x4*)(q0+36);
        t1[0]=*(const f32x4*)q1; t1[1]=*(const f32x4*)(q1+4); t1[2]=*(const f32x4*)(q1+32); t1[3]=*(const f32x4*)(q1+36);
        t2[0]=*(const f32x4*)q2; t2[1]=*(const f32x4*)(q2+4); t2[2]=*(const f32x4*)(q2+32); t2[3]=*(const f32x4*)(q2+36);
        t3[0]=*(const f32x4*)q3; t3[1]=*(const f32x4*)(q3+4); t3[2]=*(const f32x4*)(q3+32); t3[3]=*(const f32x4*)(q3+36);
        asm volatile("s_waitcnt vmcnt(12)" ::: "memory");
        { short8 a=pack8(t0[0],t0[1]), b=pack8(t0[2],t0[3]);
          char* d = smem + 0     + wfrag; *(short8*)d=a; *(short8*)(d+1024)=b; }
        asm volatile("s_waitcnt vmcnt(8)" ::: "memory");
        { short8 a=pack8(t1[0],t1[1]), b=pack8(t1[2],t1[3]);
          char* d = smem + 16384 + wfrag; *(short8*)d=a; *(short8*)(d+1024)=b; }
        asm volatile("s_waitcnt vmcnt(4)" ::: "memory");
        { short8 a=pack8(t2[0],t2[1]), b=pack8(t2[2],t2[3]);
          char* d = smem + 32768 + wfrag; *(short8*)d=a; *(short8*)(d+1024)=b; }
        asm volatile("s_waitcnt vmcnt(0)" ::: "memory");
        { short8 a=pack8(t3[0],t3[1]), b=pack8(t3[2],t3[3]);
          char* d = smem + 49152 + wfrag; *(short8*)d=a; *(short8*)(d+1024)=b; }
        // q4 = A half0 of tile1 (type0 -> S0), q5 = A half1 (type1 -> S1)
        const float* q4 = As + 64;
        const float* q5 = As + 64 + 65536;
        s0[0]=*(const f32x4*)q4; s0[1]=*(const f32x4*)(q4+4); s0[2]=*(const f32x4*)(q4+32); s0[3]=*(const f32x4*)(q4+36);
        s1[0]=*(const f32x4*)q5; s1[1]=*(const f32x4*)(q5+4); s1[2]=*(const f32x4*)(q5+32); s1[3]=*(const f32x4*)(q5+36);
        asm volatile("s_waitcnt lgkmcnt(0)" ::: "memory");
        __builtin_amdgcn_sched_barrier(0);
        __builtin_amdgcn_s_barrier();
    }

    f32x4 acc[8][4];
#pragma unroll
    for (int i = 0; i < 8; ++i)
#pragma unroll
        for (int p = 0; p < 4; ++p)
            acc[i][p] = (f32x4)0.0f;

    short8 av[4], bv[4];

#pragma unroll 1
    for (int kt = 0; kt < 6; ++kt) {
        PHASE(0, kt, s0, true, true, 4);
        PHASE(1, kt, s1, true, true, 4);
        PHASE(2, kt, s0, true, true, 4);
        PHASE(3, kt, s1, true, true, 4);
    }
    // kt=6: last issues are B0/B1 of tile 7 at p=0,1
    PHASE(0, 6, s0, true, true, 4);
    PHASE(1, 6, s1, true, true, 4);
    PHASE(2, 6, s0, true, false, 4);
    PHASE(3, 6, s1, true, false, 0);
    // kt=7: compute only
    PHASE(0, 7, s0, false, false, 0);
    PHASE(1, 7, s1, false, false, 0);
    PHASE(2, 7, s0, false, false, 0);
    PHASE(3, 7, s1, false, false, 0);

    // ---- fused epilogue: partial over this block's 256 n-cols ----
    const int nc = lane & 15;
    const int kq = lane >> 4;
    float b1v[4], w2v[4];
#pragma unroll
    for (int pp = 0; pp < 4; ++pp) {
        int n = nt * 256 + wn * 64 + pp * 16 + nc;
        b1v[pp] = B1[km * 512 + n];
        w2v[pp] = W2[km * 512 + n];
    }

    float* lout = (float*)smem;   // [256 rows][4 wn]; LDS reads all done
#pragma unroll
    for (int i = 0; i < 8; ++i) {
#pragma unroll
        for (int r = 0; r < 4; ++r) {
            float s = 0.f;
#pragma unroll
            for (int pp = 0; pp < 4; ++pp) {
                float h = acc[i][pp][r] + b1v[pp];
                h = h > 0.f ? h : 0.f;
                s += h * w2v[pp];
            }
#pragma unroll
            for (int d = 1; d < 16; d <<= 1)
                s += __shfl_xor(s, d, 64);
            if (nc == 0) {
                int row = wm * 128 + i * 16 + kq * 4 + r;
                lout[row * 4 + wn] = s;
            }
        }
    }
    __syncthreads();
    if (t < 256) {
        float s = lout[t * 4 + 0] + lout[t * 4 + 1] + lout[t * 4 + 2] + lout[t * 4 + 3];
        if (nt == 0) s += B2[km];
        int b = mt * 256 + t;
        // out[b, e, o] with k = o*E + e  ->  flat b*512 + (km%8)*64 + (km/8)
        atomicAdd(out + (size_t)b * 512 + (km & 7) * 64 + (km >> 3), s);
    }
}

extern "C" void kernel_launch(void* const* d_in, const int* in_sizes, int n_in,
                              void* d_out, int out_size, void* d_ws, size_t ws_size,
                              hipStream_t stream) {
    const float* X  = (const float*)d_in[0];
    const float* W1 = (const float*)d_in[1];
    const float* B1 = (const float*)d_in[2];
    const float* W2 = (const float*)d_in[3];
    const float* B2 = (const float*)d_in[4];
    float* out = (float*)d_out;

    hipMemsetAsync(out, 0, (size_t)out_size * sizeof(float), stream);
    ens_mlp_kernel<<<dim3(4096), dim3(512), 131072, stream>>>(X, W1, B1, W2, B2, out);
}